// Round 4
// baseline (779.064 us; speedup 1.0000x reference)
//
#include <hip/hip_runtime.h>

constexpr int NB   = 2048;
constexpr int EMB  = 16;
constexpr int NV   = 89;
constexpr int NN   = NB * NV;      // 182272 nodes (= 712 * 256)
constexpr int NEdg = 16 * NN;      // 2916352 edges (= 712 * 4096)
constexpr int H0   = 32;
constexpr int H1   = 64;
constexpr int NOUT = 3;
constexpr int NBKT = NN / 256;     // 712 buckets of 256 nodes
constexpr int EPB  = NEdg / NBKT;  // 4096 edges per hist/scatter block
constexpr float BN_EPS = 1e-5f;

// ---- pass A: per-block LDS histogram -> blkOff[block][bucket] (no atomics) ----
__global__ __launch_bounds__(256) void k_hist(const int* __restrict__ dst,
                                              int* __restrict__ blkOff) {
  __shared__ int h[NBKT];
  int t = threadIdx.x, b = blockIdx.x;
  for (int i = t; i < NBKT; i += 256) h[i] = 0;
  __syncthreads();
  int base = b * EPB;
  #pragma unroll
  for (int k = 0; k < EPB / 256; ++k)
    atomicAdd(&h[dst[base + t + k * 256] >> 8], 1);
  __syncthreads();
  for (int i = t; i < NBKT; i += 256) blkOff[(size_t)b * NBKT + i] = h[i];
}

// ---- per-bucket column scan: blkOff becomes exclusive offsets; bktCnt = totals ----
__global__ __launch_bounds__(256) void k_colscan(int* __restrict__ blkOff,
                                                 int* __restrict__ bktCnt) {
  __shared__ int s[256];
  int t = threadIdx.x, k = blockIdx.x;
  int b0 = t * 3;
  int v0 = (b0     < NBKT) ? blkOff[(size_t)(b0    ) * NBKT + k] : 0;
  int v1 = (b0 + 1 < NBKT) ? blkOff[(size_t)(b0 + 1) * NBKT + k] : 0;
  int v2 = (b0 + 2 < NBKT) ? blkOff[(size_t)(b0 + 2) * NBKT + k] : 0;
  int ts = v0 + v1 + v2;
  s[t] = ts;
  __syncthreads();
  for (int off = 1; off < 256; off <<= 1) {
    int a = (t >= off) ? s[t - off] : 0;
    __syncthreads();
    s[t] += a;
    __syncthreads();
  }
  int pre = s[t] - ts;
  if (b0     < NBKT) blkOff[(size_t)(b0    ) * NBKT + k] = pre;
  if (b0 + 1 < NBKT) blkOff[(size_t)(b0 + 1) * NBKT + k] = pre + v0;
  if (b0 + 2 < NBKT) blkOff[(size_t)(b0 + 2) * NBKT + k] = pre + v0 + v1;
  if (t == 255) bktCnt[k] = s[255];
}

// ---- bucket scan: bktCnt -> bktPtr (exclusive) ----
__global__ void k_scanB(const int* __restrict__ bktCnt, int* __restrict__ bktPtr) {
  __shared__ int s[1024];
  int t = threadIdx.x;
  int v = (t < NBKT) ? bktCnt[t] : 0;
  s[t] = v;
  __syncthreads();
  for (int off = 1; off < 1024; off <<= 1) {
    int a = (t >= off) ? s[t - off] : 0;
    __syncthreads();
    s[t] += a;
    __syncthreads();
  }
  if (t < NBKT) bktPtr[t] = s[t] - v;
}

// ---- pass B: place records at exact slots (LDS cursors, no global atomics) ----
__global__ __launch_bounds__(256) void k_scat(const int* __restrict__ src,
                                              const int* __restrict__ dst,
                                              const float* __restrict__ ew,
                                              const int* __restrict__ blkOff,
                                              const int* __restrict__ bktPtr,
                                              uint2* __restrict__ recs) {
  __shared__ int cur[NBKT];
  int t = threadIdx.x, b = blockIdx.x;
  for (int i = t; i < NBKT; i += 256)
    cur[i] = bktPtr[i] + blkOff[(size_t)b * NBKT + i];
  __syncthreads();
  int base = b * EPB;
  #pragma unroll
  for (int k = 0; k < EPB / 256; ++k) {
    int e = base + t + k * 256;
    int d = dst[e];
    int p = atomicAdd(&cur[d >> 8], 1);
    recs[p] = make_uint2(((unsigned)src[e] << 8) | (unsigned)(d & 255),
                         __float_as_uint(ew[e]));
  }
}

// ---- degree from bucket records -> dinv ----
__global__ __launch_bounds__(256) void k_deg2(const int* __restrict__ bktPtr,
                                              const int* __restrict__ bktCnt,
                                              const uint2* __restrict__ recs,
                                              float* __restrict__ dinv) {
  __shared__ float dg[256];
  int t = threadIdx.x, k = blockIdx.x;
  dg[t] = 0.f;
  __syncthreads();
  int beg = bktPtr[k], end = beg + bktCnt[k];
  for (int i = beg + t; i < end; i += 256) {
    uint2 r = recs[i];
    atomicAdd(&dg[r.x & 255], __uint_as_float(r.y));
  }
  __syncthreads();
  dinv[k * 256 + t] = rsqrtf(dg[t] + 1.0f);
}

// ---- expand: x[n][0:32] = ge[g] @ Wexp[:, v*32:(v+1)*32] + bexp ----
__global__ void k_expand(const float* __restrict__ ge, const float* __restrict__ Wexp,
                         const float* __restrict__ bexp, float* __restrict__ x) {
  int tid = blockIdx.x * 256 + threadIdx.x;
  if (tid >= NN * 8) return;
  int n = tid >> 3, q = tid & 7;
  int g = n / NV, v = n - g * NV;
  int col = v * H0 + q * 4;
  float4 acc = *(const float4*)(bexp + col);
  const float* gp = ge + g * EMB;
  #pragma unroll
  for (int k = 0; k < EMB; ++k) {
    float gk = gp[k];
    float4 w = *(const float4*)(Wexp + (size_t)k * (NV * H0) + col);
    acc.x += gk * w.x; acc.y += gk * w.y; acc.z += gk * w.z; acc.w += gk * w.w;
  }
  *(float4*)(x + (size_t)n * H0 + q * 4) = acc;
}

// ---- layer 1: LDS aggregation over bucket + fused W1/BN/ReLU/W2 -> z[N,4] ----
__global__ __launch_bounds__(256) void k_l1(
    const int* __restrict__ bktPtr, const int* __restrict__ bktCnt,
    const uint2* __restrict__ recs, const float* __restrict__ dinv,
    const float* __restrict__ x,
    const float* __restrict__ W1, const float* __restrict__ b1,
    const float* __restrict__ W2,
    const float* __restrict__ gamma, const float* __restrict__ beta,
    const float* __restrict__ mean, const float* __restrict__ var,
    float* __restrict__ z) {
  __shared__ float agg[256 * 33];          // row stride 33: conflict-free
  __shared__ float W1s[H0 * H1];
  __shared__ float W2s[H1 * NOUT];
  __shared__ float scale_s[H1], shift_s[H1];
  int t = threadIdx.x, k = blockIdx.x;
  int nbase = k * 256;
  for (int i = t; i < H0 * H1; i += 256) W1s[i] = W1[i];
  if (t < H1 * NOUT) W2s[t] = W2[t];
  if (t < H1) {
    float sc = gamma[t] * rsqrtf(var[t] + BN_EPS);
    scale_s[t] = sc;
    shift_s[t] = beta[t] + (b1[t] - mean[t]) * sc;
  }
  // init agg with self-loop term: dinv[n] * x[n]
  for (int i = t; i < 256 * H0; i += 256) {
    int row = i >> 5, fl = i & 31;
    agg[row * 33 + fl] = dinv[nbase + row] * x[(size_t)(nbase + row) * H0 + fl];
  }
  __syncthreads();
  int w = t >> 6, lane = t & 63, half = lane >> 5, fl = lane & 31;
  int beg = bktPtr[k], end = beg + bktCnt[k];
  // 4 recs per wave-iteration (2 per 32-lane half, unrolled for ILP)
  for (int base = beg + w * 4; base < end; base += 16) {
    int ri0 = base + half * 2;
    if (ri0 < end) {
      uint2 r0 = recs[ri0];
      int s0 = r0.x >> 8, row0 = r0.x & 255;
      float f0 = dinv[s0] * __uint_as_float(r0.y);
      float x0 = x[(size_t)s0 * H0 + fl];
      if (ri0 + 1 < end) {
        uint2 r1 = recs[ri0 + 1];
        int s1 = r1.x >> 8, row1 = r1.x & 255;
        float f1 = dinv[s1] * __uint_as_float(r1.y);
        float x1 = x[(size_t)s1 * H0 + fl];
        atomicAdd(&agg[row0 * 33 + fl], f0 * x0);
        atomicAdd(&agg[row1 * 33 + fl], f1 * x1);
      } else {
        atomicAdd(&agg[row0 * 33 + fl], f0 * x0);
      }
    }
  }
  __syncthreads();
  // transform: wave w handles nodes w*64 .. w*64+63
  for (int i = 0; i < 64; ++i) {
    int nl = w * 64 + i;
    int n = nbase + nl;
    float dd = dinv[n];
    float tk = 0.f;
    if (lane < H0) tk = dd * agg[nl * 33 + lane];
    float y = 0.f;
    #pragma unroll
    for (int kk = 0; kk < H0; ++kk) {
      y += __shfl(tk, kk) * W1s[kk * H1 + lane];
    }
    y = fmaxf(y * scale_s[lane] + shift_s[lane], 0.f);
    float p0 = y * W2s[lane * 3 + 0];
    float p1 = y * W2s[lane * 3 + 1];
    float p2 = y * W2s[lane * 3 + 2];
    #pragma unroll
    for (int off = 32; off; off >>= 1) {
      p0 += __shfl_xor(p0, off);
      p1 += __shfl_xor(p1, off);
      p2 += __shfl_xor(p2, off);
    }
    if (lane == 0) {
      float* zp = z + (size_t)n * 4;
      zp[0] = p0; zp[1] = p1; zp[2] = p2; zp[3] = 0.f;
    }
  }
}

// ---- layer 2: LDS aggregation of 3-dim z messages + epilogue -> out[N,3] ----
__global__ __launch_bounds__(256) void k_l2(
    const int* __restrict__ bktPtr, const int* __restrict__ bktCnt,
    const uint2* __restrict__ recs, const float* __restrict__ dinv,
    const float* __restrict__ z, const float* __restrict__ b2,
    float* __restrict__ out) {
  __shared__ float acc[256 * 4];
  int t = threadIdx.x, k = blockIdx.x;
  int nbase = k * 256;
  #pragma unroll
  for (int c = 0; c < 4; ++c) acc[t * 4 + c] = 0.f;
  __syncthreads();
  int beg = bktPtr[k], end = beg + bktCnt[k];
  for (int i = beg + t; i < end; i += 256) {
    uint2 r = recs[i];
    int s = r.x >> 8, row = r.x & 255;
    float f = dinv[s] * __uint_as_float(r.y);
    const float4 zv = *(const float4*)(z + (size_t)s * 4);
    atomicAdd(&acc[row * 4 + 0], f * zv.x);
    atomicAdd(&acc[row * 4 + 1], f * zv.y);
    atomicAdd(&acc[row * 4 + 2], f * zv.z);
  }
  __syncthreads();
  int n = nbase + t;
  float dd = dinv[n];
  const float4 zn = *(const float4*)(z + (size_t)n * 4);
  float* op = out + (size_t)n * 3;
  op[0] = b2[0] + dd * (acc[t * 4 + 0] + dd * zn.x);
  op[1] = b2[1] + dd * (acc[t * 4 + 1] + dd * zn.y);
  op[2] = b2[2] + dd * (acc[t * 4 + 2] + dd * zn.z);
}

extern "C" void kernel_launch(void* const* d_in, const int* in_sizes, int n_in,
                              void* d_out, int out_size, void* d_ws, size_t ws_size,
                              hipStream_t stream) {
  const float* ge   = (const float*)d_in[0];
  const int*   ei   = (const int*)d_in[1];
  const float* ew   = (const float*)d_in[2];
  const float* Wexp = (const float*)d_in[3];
  const float* bexp = (const float*)d_in[4];
  const float* W1   = (const float*)d_in[5];
  const float* b1   = (const float*)d_in[6];
  const float* W2   = (const float*)d_in[7];
  const float* b2   = (const float*)d_in[8];
  const float* gam  = (const float*)d_in[9];
  const float* bet  = (const float*)d_in[10];
  const float* mu   = (const float*)d_in[11];
  const float* var  = (const float*)d_in[12];
  const int* src = ei;
  const int* dst = ei + NEdg;
  float* out = (float*)d_out;

  // workspace layout (recs first: 16B-aligned; everything fully overwritten
  // before being read -> no memset needed)
  uint2* recs   = (uint2*)d_ws;                         // NEdg * 8B
  float* fws    = (float*)(recs + NEdg);
  float* dinv   = fws;                                   // NN
  float* x      = fws + NN;                              // NN*32
  float* z      = x + (size_t)NN * H0;                   // NN*4 (padded)
  int*   blkOff = (int*)(z + (size_t)NN * 4);            // NBKT*NBKT
  int*   bktCnt = blkOff + (size_t)NBKT * NBKT;          // NBKT
  int*   bktPtr = bktCnt + NBKT;                         // NBKT

  k_hist   <<<NBKT, 256, 0, stream>>>(dst, blkOff);
  k_colscan<<<NBKT, 256, 0, stream>>>(blkOff, bktCnt);
  k_scanB  <<<1, 1024, 0, stream>>>(bktCnt, bktPtr);
  k_scat   <<<NBKT, 256, 0, stream>>>(src, dst, ew, blkOff, bktPtr, recs);
  k_deg2   <<<NBKT, 256, 0, stream>>>(bktPtr, bktCnt, recs, dinv);
  k_expand <<<NN * 8 / 256, 256, 0, stream>>>(ge, Wexp, bexp, x);
  k_l1     <<<NBKT, 256, 0, stream>>>(bktPtr, bktCnt, recs, dinv, x,
                                      W1, b1, W2, gam, bet, mu, var, z);
  k_l2     <<<NBKT, 256, 0, stream>>>(bktPtr, bktCnt, recs, dinv, z, b2, out);
}

// Round 5
// 342.703 us; speedup vs baseline: 2.2733x; 2.2733x over previous
//
#include <hip/hip_runtime.h>

constexpr int NB   = 2048;
constexpr int EMB  = 16;
constexpr int NV   = 89;
constexpr int NN   = NB * NV;      // 182272 nodes (= 712 * 256)
constexpr int NEdg = 16 * NN;      // 2916352 edges (= 712 * 4096)
constexpr int H0   = 32;
constexpr int H1   = 64;
constexpr int NOUT = 3;
constexpr int NBKT = NN / 256;     // 712 buckets of 256 nodes
constexpr int EPB  = NEdg / NBKT;  // 4096 edges per hist/scatter block
constexpr float BN_EPS = 1e-5f;

// ---- pass A: per-block LDS histogram -> blkOff[block][bucket] ----
__global__ __launch_bounds__(256) void k_hist(const int* __restrict__ dst,
                                              int* __restrict__ blkOff) {
  __shared__ int h[NBKT];
  int t = threadIdx.x, b = blockIdx.x;
  for (int i = t; i < NBKT; i += 256) h[i] = 0;
  __syncthreads();
  int base = b * EPB;
  #pragma unroll
  for (int k = 0; k < EPB / 256; ++k)
    atomicAdd(&h[dst[base + t + k * 256] >> 8], 1);
  __syncthreads();
  for (int i = t; i < NBKT; i += 256) blkOff[(size_t)b * NBKT + i] = h[i];
}

// ---- per-bucket column scan over blocks; bktCnt = totals ----
__global__ __launch_bounds__(256) void k_colscan(int* __restrict__ blkOff,
                                                 int* __restrict__ bktCnt) {
  __shared__ int s[256];
  int t = threadIdx.x, k = blockIdx.x;
  int b0 = t * 3;
  int v0 = (b0     < NBKT) ? blkOff[(size_t)(b0    ) * NBKT + k] : 0;
  int v1 = (b0 + 1 < NBKT) ? blkOff[(size_t)(b0 + 1) * NBKT + k] : 0;
  int v2 = (b0 + 2 < NBKT) ? blkOff[(size_t)(b0 + 2) * NBKT + k] : 0;
  int ts = v0 + v1 + v2;
  s[t] = ts;
  __syncthreads();
  for (int off = 1; off < 256; off <<= 1) {
    int a = (t >= off) ? s[t - off] : 0;
    __syncthreads();
    s[t] += a;
    __syncthreads();
  }
  int pre = s[t] - ts;
  if (b0     < NBKT) blkOff[(size_t)(b0    ) * NBKT + k] = pre;
  if (b0 + 1 < NBKT) blkOff[(size_t)(b0 + 1) * NBKT + k] = pre + v0;
  if (b0 + 2 < NBKT) blkOff[(size_t)(b0 + 2) * NBKT + k] = pre + v0 + v1;
  if (t == 255) bktCnt[k] = s[255];
}

// ---- bucket scan: bktCnt -> bktPtr (exclusive) ----
__global__ void k_scanB(const int* __restrict__ bktCnt, int* __restrict__ bktPtr) {
  __shared__ int s[1024];
  int t = threadIdx.x;
  int v = (t < NBKT) ? bktCnt[t] : 0;
  s[t] = v;
  __syncthreads();
  for (int off = 1; off < 1024; off <<= 1) {
    int a = (t >= off) ? s[t - off] : 0;
    __syncthreads();
    s[t] += a;
    __syncthreads();
  }
  if (t < NBKT) bktPtr[t] = s[t] - v;
}

// ---- pass B: place records bucket-grouped (LDS cursors only) ----
__global__ __launch_bounds__(256) void k_scat(const int* __restrict__ src,
                                              const int* __restrict__ dst,
                                              const float* __restrict__ ew,
                                              const int* __restrict__ blkOff,
                                              const int* __restrict__ bktPtr,
                                              uint2* __restrict__ recs) {
  __shared__ int cur[NBKT];
  int t = threadIdx.x, b = blockIdx.x;
  for (int i = t; i < NBKT; i += 256)
    cur[i] = bktPtr[i] + blkOff[(size_t)b * NBKT + i];
  __syncthreads();
  int base = b * EPB;
  #pragma unroll
  for (int k = 0; k < EPB / 256; ++k) {
    int e = base + t + k * 256;
    int d = dst[e];
    int p = atomicAdd(&cur[d >> 8], 1);
    recs[p] = make_uint2(((unsigned)src[e] << 8) | (unsigned)(d & 255),
                         __float_as_uint(ew[e]));
  }
}

// ---- degree from bucket records -> dinv ----
__global__ __launch_bounds__(256) void k_deg2(const int* __restrict__ bktPtr,
                                              const int* __restrict__ bktCnt,
                                              const uint2* __restrict__ recs,
                                              float* __restrict__ dinv) {
  __shared__ float dg[256];
  int t = threadIdx.x, k = blockIdx.x;
  dg[t] = 0.f;
  __syncthreads();
  int beg = bktPtr[k], end = beg + bktCnt[k];
  for (int i = beg + t; i < end; i += 256) {
    uint2 r = recs[i];
    atomicAdd(&dg[r.x & 255], __uint_as_float(r.y));
  }
  __syncthreads();
  dinv[k * 256 + t] = rsqrtf(dg[t] + 1.0f);
}

// ---- pass C: in-bucket sort by node -> recs2 (f precomputed) + rowptr ----
__global__ __launch_bounds__(256) void k_sort2(
    const int* __restrict__ bktPtr, const int* __restrict__ bktCnt,
    const uint2* __restrict__ recs, const float* __restrict__ dinv,
    uint2* __restrict__ recs2, int* __restrict__ rowptr) {
  __shared__ int sc[256];
  __shared__ int cur[256];
  int t = threadIdx.x, k = blockIdx.x;
  sc[t] = 0;
  __syncthreads();
  int beg = bktPtr[k], cnt = bktCnt[k];
  for (int i = t; i < cnt; i += 256)
    atomicAdd(&sc[recs[beg + i].x & 255], 1);
  __syncthreads();
  int v = sc[t];
  __syncthreads();
  sc[t] = v;
  __syncthreads();
  for (int off = 1; off < 256; off <<= 1) {
    int a = (t >= off) ? sc[t - off] : 0;
    __syncthreads();
    sc[t] += a;
    __syncthreads();
  }
  int excl = beg + sc[t] - v;
  cur[t] = excl;
  rowptr[k * 256 + t] = excl;
  if (k == NBKT - 1 && t == 0) rowptr[NN] = NEdg;
  __syncthreads();
  for (int i = t; i < cnt; i += 256) {
    uint2 r = recs[beg + i];
    int p = atomicAdd(&cur[r.x & 255], 1);
    int s = r.x >> 8;
    recs2[p] = make_uint2(r.x, __float_as_uint(dinv[s] * __uint_as_float(r.y)));
  }
}

// ---- expand: x[n][0:32] = ge[g] @ Wexp[:, v*32:(v+1)*32] + bexp ----
__global__ void k_expand(const float* __restrict__ ge, const float* __restrict__ Wexp,
                         const float* __restrict__ bexp, float* __restrict__ x) {
  int tid = blockIdx.x * 256 + threadIdx.x;
  if (tid >= NN * 8) return;
  int n = tid >> 3, q = tid & 7;
  int g = n / NV, v = n - g * NV;
  int col = v * H0 + q * 4;
  float4 acc = *(const float4*)(bexp + col);
  const float* gp = ge + g * EMB;
  #pragma unroll
  for (int k = 0; k < EMB; ++k) {
    float gk = gp[k];
    float4 w = *(const float4*)(Wexp + (size_t)k * (NV * H0) + col);
    acc.x += gk * w.x; acc.y += gk * w.y; acc.z += gk * w.z; acc.w += gk * w.w;
  }
  *(float4*)(x + (size_t)n * H0 + q * 4) = acc;
}

// ---- layer 1: wave/node gather (8 edges x 8 float4-lanes) + W1/BN/ReLU/W2 ----
__global__ __launch_bounds__(256) void k_g1(
    const int* __restrict__ rowptr, const uint2* __restrict__ recs,
    const float* __restrict__ dinv, const float* __restrict__ x,
    const float* __restrict__ W1, const float* __restrict__ b1,
    const float* __restrict__ W2,
    const float* __restrict__ gamma, const float* __restrict__ beta,
    const float* __restrict__ mean, const float* __restrict__ var,
    float* __restrict__ z) {
  __shared__ float W1s[H0 * H1];
  __shared__ float W2s[H1 * NOUT];
  __shared__ float scale_s[H1], shift_s[H1];
  int t = threadIdx.x;
  for (int i = t; i < H0 * H1; i += 256) W1s[i] = W1[i];
  if (t < H1 * NOUT) W2s[t] = W2[t];
  if (t < H1) {
    float sc = gamma[t] * rsqrtf(var[t] + BN_EPS);
    scale_s[t] = sc;
    shift_s[t] = beta[t] + (b1[t] - mean[t]) * sc;
  }
  __syncthreads();
  int w = t >> 6, lane = t & 63;
  int n = blockIdx.x * 4 + w;
  int beg = rowptr[n], end = rowptr[n + 1];
  int j = lane >> 3, q = lane & 7;           // edge slot, feature quarter
  float4 acc = make_float4(0.f, 0.f, 0.f, 0.f);
  for (int base = beg; base < end; base += 8) {
    uint2 r = make_uint2(0u, 0u);
    if (lane < 8 && base + lane < end) r = recs[base + lane];
    unsigned rx = (unsigned)__shfl((int)r.x, j);
    float f = __shfl(__uint_as_float(r.y), j);
    if (base + j < end) {
      int s = rx >> 8;
      const float4 xv = *(const float4*)(x + (size_t)s * H0 + q * 4);
      acc.x += f * xv.x; acc.y += f * xv.y; acc.z += f * xv.z; acc.w += f * xv.w;
    }
  }
  #pragma unroll
  for (int off = 8; off < 64; off <<= 1) {
    acc.x += __shfl_xor(acc.x, off);
    acc.y += __shfl_xor(acc.y, off);
    acc.z += __shfl_xor(acc.z, off);
    acc.w += __shfl_xor(acc.w, off);
  }
  float dd = dinv[n];
  {  // self-loop (post-reduction; every lane adds same value for its q)
    const float4 xn = *(const float4*)(x + (size_t)n * H0 + q * 4);
    acc.x += dd * xn.x; acc.y += dd * xn.y; acc.z += dd * xn.z; acc.w += dd * xn.w;
  }
  // redistribute: lane l (0..31) needs feature l from lane l>>2's component l&3
  int srcl = (lane & 31) >> 2;
  float a0 = __shfl(acc.x, srcl);
  float a1 = __shfl(acc.y, srcl);
  float a2 = __shfl(acc.z, srcl);
  float a3 = __shfl(acc.w, srcl);
  int c = lane & 3;
  float tk = (c == 0) ? a0 : (c == 1) ? a1 : (c == 2) ? a2 : a3;
  tk *= dd;
  float y = 0.f;
  #pragma unroll
  for (int kk = 0; kk < H0; ++kk) {
    y += __shfl(tk, kk) * W1s[kk * H1 + lane];
  }
  y = fmaxf(y * scale_s[lane] + shift_s[lane], 0.f);
  float p0 = y * W2s[lane * 3 + 0];
  float p1 = y * W2s[lane * 3 + 1];
  float p2 = y * W2s[lane * 3 + 2];
  #pragma unroll
  for (int off = 32; off; off >>= 1) {
    p0 += __shfl_xor(p0, off);
    p1 += __shfl_xor(p1, off);
    p2 += __shfl_xor(p2, off);
  }
  if (lane == 0) {
    float* zp = z + (size_t)n * 4;
    zp[0] = p0; zp[1] = p1; zp[2] = p2; zp[3] = 0.f;
  }
}

// ---- layer 2: 4 lanes/node gather of z (f precomputed) -> out ----
__global__ __launch_bounds__(256) void k_g2(
    const int* __restrict__ rowptr, const uint2* __restrict__ recs,
    const float* __restrict__ dinv, const float* __restrict__ z,
    const float* __restrict__ b2, float* __restrict__ out) {
  int t = threadIdx.x;
  int wave = t >> 6, lane = t & 63;
  int nw = lane >> 2, q = lane & 3;
  int n = blockIdx.x * 64 + wave * 16 + nw;
  int beg = rowptr[n], end = rowptr[n + 1];
  float a0 = 0.f, a1 = 0.f, a2 = 0.f;
  for (int i = beg + q; i < end; i += 4) {
    uint2 r = recs[i];
    int s = (int)(r.x >> 8);
    float f = __uint_as_float(r.y);
    const float4 zv = *(const float4*)(z + (size_t)s * 4);
    a0 += f * zv.x; a1 += f * zv.y; a2 += f * zv.z;
  }
  a0 += __shfl_xor(a0, 1); a0 += __shfl_xor(a0, 2);
  a1 += __shfl_xor(a1, 1); a1 += __shfl_xor(a1, 2);
  a2 += __shfl_xor(a2, 1); a2 += __shfl_xor(a2, 2);
  if (q == 0) {
    float dd = dinv[n];
    const float4 zn = *(const float4*)(z + (size_t)n * 4);
    float* op = out + (size_t)n * 3;
    op[0] = b2[0] + dd * (a0 + dd * zn.x);
    op[1] = b2[1] + dd * (a1 + dd * zn.y);
    op[2] = b2[2] + dd * (a2 + dd * zn.z);
  }
}

extern "C" void kernel_launch(void* const* d_in, const int* in_sizes, int n_in,
                              void* d_out, int out_size, void* d_ws, size_t ws_size,
                              hipStream_t stream) {
  const float* ge   = (const float*)d_in[0];
  const int*   ei   = (const int*)d_in[1];
  const float* ew   = (const float*)d_in[2];
  const float* Wexp = (const float*)d_in[3];
  const float* bexp = (const float*)d_in[4];
  const float* W1   = (const float*)d_in[5];
  const float* b1   = (const float*)d_in[6];
  const float* W2   = (const float*)d_in[7];
  const float* b2   = (const float*)d_in[8];
  const float* gam  = (const float*)d_in[9];
  const float* bet  = (const float*)d_in[10];
  const float* mu   = (const float*)d_in[11];
  const float* var  = (const float*)d_in[12];
  const int* src = ei;
  const int* dst = ei + NEdg;
  float* out = (float*)d_out;

  // workspace layout (everything fully overwritten before read -> no memset)
  uint2* recs   = (uint2*)d_ws;                          // NEdg * 8B
  uint2* recs2  = recs + NEdg;                           // NEdg * 8B
  float* fws    = (float*)(recs2 + NEdg);
  float* dinv   = fws;                                   // NN
  float* x      = fws + NN;                              // NN*32
  float* z      = x + (size_t)NN * H0;                   // NN*4 (padded)
  int*   rowptr = (int*)(z + (size_t)NN * 4);            // NN+1
  int*   blkOff = rowptr + NN + 1;                       // NBKT*NBKT
  int*   bktCnt = blkOff + (size_t)NBKT * NBKT;          // NBKT
  int*   bktPtr = bktCnt + NBKT;                         // NBKT

  k_hist   <<<NBKT, 256, 0, stream>>>(dst, blkOff);
  k_colscan<<<NBKT, 256, 0, stream>>>(blkOff, bktCnt);
  k_scanB  <<<1, 1024, 0, stream>>>(bktCnt, bktPtr);
  k_scat   <<<NBKT, 256, 0, stream>>>(src, dst, ew, blkOff, bktPtr, recs);
  k_deg2   <<<NBKT, 256, 0, stream>>>(bktPtr, bktCnt, recs, dinv);
  k_sort2  <<<NBKT, 256, 0, stream>>>(bktPtr, bktCnt, recs, dinv, recs2, rowptr);
  k_expand <<<NN * 8 / 256, 256, 0, stream>>>(ge, Wexp, bexp, x);
  k_g1     <<<NN / 4, 256, 0, stream>>>(rowptr, recs2, dinv, x,
                                        W1, b1, W2, gam, bet, mu, var, z);
  k_g2     <<<NN / 64, 256, 0, stream>>>(rowptr, recs2, dinv, z, b2, out);
}

// Round 6
// 332.122 us; speedup vs baseline: 2.3457x; 1.0319x over previous
//
#include <hip/hip_runtime.h>
#include <hip/hip_fp16.h>

constexpr int NB   = 2048;
constexpr int EMB  = 16;
constexpr int NV   = 89;
constexpr int NN   = NB * NV;      // 182272 nodes (= 712 * 256)
constexpr int NEdg = 16 * NN;      // 2916352 edges (= 712 * 4096)
constexpr int H0   = 32;
constexpr int H1   = 64;
constexpr int NOUT = 3;
constexpr int NBKT = NN / 256;     // 712 buckets of 256 nodes
constexpr int EPB  = NEdg / NBKT;  // 4096 edges per hist/scatter block
constexpr float BN_EPS = 1e-5f;

struct h4 { __half2 a, b; };       // 8B packed 4x fp16

// ---- pass A: per-block LDS histogram -> blkOff[block][bucket] ----
__global__ __launch_bounds__(256) void k_hist(const int* __restrict__ dst,
                                              int* __restrict__ blkOff) {
  __shared__ int h[NBKT];
  int t = threadIdx.x, b = blockIdx.x;
  for (int i = t; i < NBKT; i += 256) h[i] = 0;
  __syncthreads();
  int base = b * EPB;
  #pragma unroll
  for (int k = 0; k < EPB / 256; ++k)
    atomicAdd(&h[dst[base + t + k * 256] >> 8], 1);
  __syncthreads();
  for (int i = t; i < NBKT; i += 256) blkOff[(size_t)b * NBKT + i] = h[i];
}

// ---- per-bucket column scan over blocks; bktCnt = totals ----
__global__ __launch_bounds__(256) void k_colscan(int* __restrict__ blkOff,
                                                 int* __restrict__ bktCnt) {
  __shared__ int s[256];
  int t = threadIdx.x, k = blockIdx.x;
  int b0 = t * 3;
  int v0 = (b0     < NBKT) ? blkOff[(size_t)(b0    ) * NBKT + k] : 0;
  int v1 = (b0 + 1 < NBKT) ? blkOff[(size_t)(b0 + 1) * NBKT + k] : 0;
  int v2 = (b0 + 2 < NBKT) ? blkOff[(size_t)(b0 + 2) * NBKT + k] : 0;
  int ts = v0 + v1 + v2;
  s[t] = ts;
  __syncthreads();
  for (int off = 1; off < 256; off <<= 1) {
    int a = (t >= off) ? s[t - off] : 0;
    __syncthreads();
    s[t] += a;
    __syncthreads();
  }
  int pre = s[t] - ts;
  if (b0     < NBKT) blkOff[(size_t)(b0    ) * NBKT + k] = pre;
  if (b0 + 1 < NBKT) blkOff[(size_t)(b0 + 1) * NBKT + k] = pre + v0;
  if (b0 + 2 < NBKT) blkOff[(size_t)(b0 + 2) * NBKT + k] = pre + v0 + v1;
  if (t == 255) bktCnt[k] = s[255];
}

// ---- bucket scan: bktCnt -> bktPtr (exclusive) ----
__global__ void k_scanB(const int* __restrict__ bktCnt, int* __restrict__ bktPtr) {
  __shared__ int s[1024];
  int t = threadIdx.x;
  int v = (t < NBKT) ? bktCnt[t] : 0;
  s[t] = v;
  __syncthreads();
  for (int off = 1; off < 1024; off <<= 1) {
    int a = (t >= off) ? s[t - off] : 0;
    __syncthreads();
    s[t] += a;
    __syncthreads();
  }
  if (t < NBKT) bktPtr[t] = s[t] - v;
}

// ---- pass B: place records bucket-grouped (LDS cursors only) ----
__global__ __launch_bounds__(256) void k_scat(const int* __restrict__ src,
                                              const int* __restrict__ dst,
                                              const float* __restrict__ ew,
                                              const int* __restrict__ blkOff,
                                              const int* __restrict__ bktPtr,
                                              uint2* __restrict__ recs) {
  __shared__ int cur[NBKT];
  int t = threadIdx.x, b = blockIdx.x;
  for (int i = t; i < NBKT; i += 256)
    cur[i] = bktPtr[i] + blkOff[(size_t)b * NBKT + i];
  __syncthreads();
  int base = b * EPB;
  #pragma unroll
  for (int k = 0; k < EPB / 256; ++k) {
    int e = base + t + k * 256;
    int d = dst[e];
    int p = atomicAdd(&cur[d >> 8], 1);
    recs[p] = make_uint2(((unsigned)src[e] << 8) | (unsigned)(d & 255),
                         __float_as_uint(ew[e]));
  }
}

// ---- pass C: in-bucket sort by node -> recs2 + rowptr + fused degree->dinv ----
__global__ __launch_bounds__(256) void k_sort2(
    const int* __restrict__ bktPtr, const int* __restrict__ bktCnt,
    const uint2* __restrict__ recs,
    uint2* __restrict__ recs2, int* __restrict__ rowptr,
    float* __restrict__ dinv) {
  __shared__ int sc[256];
  __shared__ int cur[256];
  __shared__ float dg[256];
  int t = threadIdx.x, k = blockIdx.x;
  sc[t] = 0;
  dg[t] = 0.f;
  __syncthreads();
  int beg = bktPtr[k], cnt = bktCnt[k];
  for (int i = t; i < cnt; i += 256) {
    uint2 r = recs[beg + i];
    atomicAdd(&sc[r.x & 255], 1);
    atomicAdd(&dg[r.x & 255], __uint_as_float(r.y));
  }
  __syncthreads();
  dinv[k * 256 + t] = rsqrtf(dg[t] + 1.0f);
  int v = sc[t];
  __syncthreads();
  sc[t] = v;
  __syncthreads();
  for (int off = 1; off < 256; off <<= 1) {
    int a = (t >= off) ? sc[t - off] : 0;
    __syncthreads();
    sc[t] += a;
    __syncthreads();
  }
  int excl = beg + sc[t] - v;
  cur[t] = excl;
  rowptr[k * 256 + t] = excl;
  if (k == NBKT - 1 && t == 0) rowptr[NN] = NEdg;
  __syncthreads();
  for (int i = t; i < cnt; i += 256) {
    uint2 r = recs[beg + i];
    int p = atomicAdd(&cur[r.x & 255], 1);
    recs2[p] = r;                      // keep raw {src<<8|row, w}
  }
}

// ---- expand: x[n][0:32] = ge[g] @ Wexp[:, v*32:(v+1)*32] + bexp  (fp16 out) ----
__global__ void k_expand(const float* __restrict__ ge, const float* __restrict__ Wexp,
                         const float* __restrict__ bexp, __half* __restrict__ xh) {
  int tid = blockIdx.x * 256 + threadIdx.x;
  if (tid >= NN * 8) return;
  int n = tid >> 3, q = tid & 7;
  int g = n / NV, v = n - g * NV;
  int col = v * H0 + q * 4;
  float4 acc = *(const float4*)(bexp + col);
  const float* gp = ge + g * EMB;
  #pragma unroll
  for (int k = 0; k < EMB; ++k) {
    float gk = gp[k];
    float4 w = *(const float4*)(Wexp + (size_t)k * (NV * H0) + col);
    acc.x += gk * w.x; acc.y += gk * w.y; acc.z += gk * w.z; acc.w += gk * w.w;
  }
  h4 o;
  o.a = __floats2half2_rn(acc.x, acc.y);
  o.b = __floats2half2_rn(acc.z, acc.w);
  *(h4*)(xh + (size_t)n * H0 + q * 4) = o;
}

// ---- layer 1: wave/node gather (hoisted rec prefetch, fp16 x) + transform ----
__global__ __launch_bounds__(256) void k_g1(
    const int* __restrict__ rowptr, const uint2* __restrict__ recs,
    const float* __restrict__ dinv, const __half* __restrict__ xh,
    const float* __restrict__ W1, const float* __restrict__ b1,
    const float* __restrict__ W2,
    const float* __restrict__ gamma, const float* __restrict__ beta,
    const float* __restrict__ mean, const float* __restrict__ var,
    float* __restrict__ z) {
  __shared__ float W1s[H0 * H1];
  __shared__ float W2s[H1 * NOUT];
  __shared__ float scale_s[H1], shift_s[H1];
  int t = threadIdx.x;
  for (int i = t; i < H0 * H1; i += 256) W1s[i] = W1[i];
  if (t < H1 * NOUT) W2s[t] = W2[t];
  if (t < H1) {
    float sc = gamma[t] * rsqrtf(var[t] + BN_EPS);
    scale_s[t] = sc;
    shift_s[t] = beta[t] + (b1[t] - mean[t]) * sc;
  }
  __syncthreads();
  int w = t >> 6, lane = t & 63;
  int n = blockIdx.x * 4 + w;
  int beg = rowptr[n], end = rowptr[n + 1];
  int j = lane >> 3, q = lane & 7;           // edge slot, feature quarter
  float4 acc = make_float4(0.f, 0.f, 0.f, 0.f);
  for (int base = beg; base < end; base += 64) {   // one pass (deg<=64 always)
    int c = end - base; c = c < 64 ? c : 64;
    int s_all = 0; float f_all = 0.f;
    if (lane < c) {
      uint2 r = recs[base + lane];
      s_all = (int)(r.x >> 8);
      f_all = dinv[s_all] * __uint_as_float(r.y);
    }
    for (int b0 = 0; b0 < c; b0 += 8) {
      int jj = b0 + j;
      int s   = __shfl(s_all, jj);
      float f = __shfl(f_all, jj);
      if (jj < c) {
        h4 v = *(const h4*)(xh + (size_t)s * H0 + q * 4);
        float2 lo = __half22float2(v.a), hi = __half22float2(v.b);
        acc.x += f * lo.x; acc.y += f * lo.y; acc.z += f * hi.x; acc.w += f * hi.y;
      }
    }
  }
  #pragma unroll
  for (int off = 8; off < 64; off <<= 1) {
    acc.x += __shfl_xor(acc.x, off);
    acc.y += __shfl_xor(acc.y, off);
    acc.z += __shfl_xor(acc.z, off);
    acc.w += __shfl_xor(acc.w, off);
  }
  float dd = dinv[n];
  {  // self-loop
    h4 v = *(const h4*)(xh + (size_t)n * H0 + q * 4);
    float2 lo = __half22float2(v.a), hi = __half22float2(v.b);
    acc.x += dd * lo.x; acc.y += dd * lo.y; acc.z += dd * hi.x; acc.w += dd * hi.y;
  }
  // redistribute: lane l (0..31) needs feature l from lane l>>2's component l&3
  int srcl = (lane & 31) >> 2;
  float a0 = __shfl(acc.x, srcl);
  float a1 = __shfl(acc.y, srcl);
  float a2 = __shfl(acc.z, srcl);
  float a3 = __shfl(acc.w, srcl);
  int c4 = lane & 3;
  float tk = (c4 == 0) ? a0 : (c4 == 1) ? a1 : (c4 == 2) ? a2 : a3;
  tk *= dd;
  float y = 0.f;
  #pragma unroll
  for (int kk = 0; kk < H0; ++kk) {
    y += __shfl(tk, kk) * W1s[kk * H1 + lane];
  }
  y = fmaxf(y * scale_s[lane] + shift_s[lane], 0.f);
  float p0 = y * W2s[lane * 3 + 0];
  float p1 = y * W2s[lane * 3 + 1];
  float p2 = y * W2s[lane * 3 + 2];
  #pragma unroll
  for (int off = 32; off; off >>= 1) {
    p0 += __shfl_xor(p0, off);
    p1 += __shfl_xor(p1, off);
    p2 += __shfl_xor(p2, off);
  }
  if (lane == 0) {
    float* zp = z + (size_t)n * 4;
    zp[0] = p0; zp[1] = p1; zp[2] = p2; zp[3] = 0.f;
  }
}

// ---- layer 2: 4 lanes/node gather of z -> out ----
__global__ __launch_bounds__(256) void k_g2(
    const int* __restrict__ rowptr, const uint2* __restrict__ recs,
    const float* __restrict__ dinv, const float* __restrict__ z,
    const float* __restrict__ b2, float* __restrict__ out) {
  int t = threadIdx.x;
  int wave = t >> 6, lane = t & 63;
  int nw = lane >> 2, q = lane & 3;
  int n = blockIdx.x * 64 + wave * 16 + nw;
  int beg = rowptr[n], end = rowptr[n + 1];
  float a0 = 0.f, a1 = 0.f, a2 = 0.f;
  for (int i = beg + q; i < end; i += 4) {
    uint2 r = recs[i];
    int s = (int)(r.x >> 8);
    float f = dinv[s] * __uint_as_float(r.y);
    const float4 zv = *(const float4*)(z + (size_t)s * 4);
    a0 += f * zv.x; a1 += f * zv.y; a2 += f * zv.z;
  }
  a0 += __shfl_xor(a0, 1); a0 += __shfl_xor(a0, 2);
  a1 += __shfl_xor(a1, 1); a1 += __shfl_xor(a1, 2);
  a2 += __shfl_xor(a2, 1); a2 += __shfl_xor(a2, 2);
  if (q == 0) {
    float dd = dinv[n];
    const float4 zn = *(const float4*)(z + (size_t)n * 4);
    float* op = out + (size_t)n * 3;
    op[0] = b2[0] + dd * (a0 + dd * zn.x);
    op[1] = b2[1] + dd * (a1 + dd * zn.y);
    op[2] = b2[2] + dd * (a2 + dd * zn.z);
  }
}

extern "C" void kernel_launch(void* const* d_in, const int* in_sizes, int n_in,
                              void* d_out, int out_size, void* d_ws, size_t ws_size,
                              hipStream_t stream) {
  const float* ge   = (const float*)d_in[0];
  const int*   ei   = (const int*)d_in[1];
  const float* ew   = (const float*)d_in[2];
  const float* Wexp = (const float*)d_in[3];
  const float* bexp = (const float*)d_in[4];
  const float* W1   = (const float*)d_in[5];
  const float* b1   = (const float*)d_in[6];
  const float* W2   = (const float*)d_in[7];
  const float* b2   = (const float*)d_in[8];
  const float* gam  = (const float*)d_in[9];
  const float* bet  = (const float*)d_in[10];
  const float* mu   = (const float*)d_in[11];
  const float* var  = (const float*)d_in[12];
  const int* src = ei;
  const int* dst = ei + NEdg;
  float* out = (float*)d_out;

  // workspace layout (everything fully overwritten before read -> no memset)
  uint2*  recs   = (uint2*)d_ws;                         // NEdg * 8B
  uint2*  recs2  = recs + NEdg;                          // NEdg * 8B
  float*  dinv   = (float*)(recs2 + NEdg);               // NN
  __half* xh     = (__half*)(dinv + NN);                 // NN*32 fp16 (8B-aligned)
  float*  z      = (float*)(xh + (size_t)NN * H0);       // NN*4 (padded)
  int*    rowptr = (int*)(z + (size_t)NN * 4);           // NN+1
  int*    blkOff = rowptr + NN + 1;                      // NBKT*NBKT
  int*    bktCnt = blkOff + (size_t)NBKT * NBKT;         // NBKT
  int*    bktPtr = bktCnt + NBKT;                        // NBKT

  k_hist   <<<NBKT, 256, 0, stream>>>(dst, blkOff);
  k_colscan<<<NBKT, 256, 0, stream>>>(blkOff, bktCnt);
  k_scanB  <<<1, 1024, 0, stream>>>(bktCnt, bktPtr);
  k_scat   <<<NBKT, 256, 0, stream>>>(src, dst, ew, blkOff, bktPtr, recs);
  k_sort2  <<<NBKT, 256, 0, stream>>>(bktPtr, bktCnt, recs, recs2, rowptr, dinv);
  k_expand <<<NN * 8 / 256, 256, 0, stream>>>(ge, Wexp, bexp, xh);
  k_g1     <<<NN / 4, 256, 0, stream>>>(rowptr, recs2, dinv, xh,
                                        W1, b1, W2, gam, bet, mu, var, z);
  k_g2     <<<NN / 64, 256, 0, stream>>>(rowptr, recs2, dinv, z, b2, out);
}